// Round 2
// baseline (452.986 us; speedup 1.0000x reference)
//
#include <hip/hip_runtime.h>
#include <cstdint>
#include <cstddef>

#define SEQ 2048
#define DMODEL 1024
#define NHEADS 16
#define HDIM 64

typedef __attribute__((ext_vector_type(8))) short short8;
typedef __attribute__((ext_vector_type(4))) float floatx4;

__device__ __forceinline__ short f2bf(float f) {
  union { float f; uint32_t u; } x; x.f = f;
  uint32_t r = (x.u + 0x7FFFu + ((x.u >> 16) & 1u)) >> 16;
  return (short)(uint16_t)r;
}

__device__ __forceinline__ void gl_lds16(const short* g, short* l) {
  __builtin_amdgcn_global_load_lds((const __attribute__((address_space(1))) void*)g,
                                   (__attribute__((address_space(3))) void*)l, 16, 0, 0);
}

// ---------------- cast fp32 -> bf16 ----------------
__global__ __launch_bounds__(256) void cast_bf16_kernel(const float* __restrict__ src,
                                                        short* __restrict__ dst, int n) {
  int i = blockIdx.x * 256 + threadIdx.x;
  if (i < n) dst[i] = f2bf(src[i]);
}

// ---------------- transpose 1024x1024 fp32 -> bf16 (W[d][n] -> Wt[n][d]) ----------------
__global__ __launch_bounds__(256) void transpose_cast_kernel(const float* __restrict__ src,
                                                             short* __restrict__ dst) {
  __shared__ float tile[32][33];
  int tx = threadIdx.x, ty = threadIdx.y;
  int x = blockIdx.x * 32 + tx;
  int y0 = blockIdx.y * 32;
#pragma unroll
  for (int j = 0; j < 32; j += 8)
    tile[ty + j][tx] = src[(size_t)(y0 + ty + j) * DMODEL + x];
  __syncthreads();
  int xo = blockIdx.y * 32 + tx;
  int yo0 = blockIdx.x * 32;
#pragma unroll
  for (int j = 0; j < 32; j += 8)
    dst[(size_t)(yo0 + ty + j) * DMODEL + xo] = f2bf(tile[tx][ty + j]);
}

// ---------------- QKV GEMM: 64x128 tile, 768 blocks (3/CU), dbuf LDS, prefetch-first ----------------
// C[2048][3072] = Xb[2048][1024] * Wt^T ; q/k head-major, vT transposed via swapped-operand MFMA.
__global__ __launch_bounds__(256) void qkv_gemm_kernel(const short* __restrict__ Xb,
                                                       const short* __restrict__ Wt,
                                                       short* __restrict__ q,
                                                       short* __restrict__ k,
                                                       short* __restrict__ vT) {
  __shared__ short Ab[2][64 * 32];    // 4 KB each
  __shared__ short Bb[2][128 * 32];   // 8 KB each (24 KB total)
  int tid = threadIdx.x;
  int wave = tid >> 6, lane = tid & 63;
  int lr = lane & 15, quad = lane >> 4;
  int m0 = blockIdx.y * 64;
  int n0 = blockIdx.x * 128;
  int wr = wave >> 1, wc = wave & 1;  // wave tile: 32 rows x 64 cols

  const short* Ag = Xb + (size_t)(m0 + (tid >> 2)) * DMODEL + (tid & 3) * 8;
  const short* Bg = Wt + (size_t)(n0 + (tid >> 2)) * DMODEL + (tid & 3) * 8;
  bool isV = (n0 >= 2 * DMODEL);

  floatx4 acc[2][4] = {};

  // prologue: stage K-tile 0
  gl_lds16(Ag, Ab[0] + wave * 512);
  gl_lds16(Bg, Bb[0] + wave * 512);
  gl_lds16(Bg + 64 * DMODEL, Bb[0] + 2048 + wave * 512);
  __syncthreads();

  int cur = 0;
  for (int t = 0; t < 32; ++t) {
    // issue next-tile staging FIRST so it flies under this tile's compute
    if (t < 31) {
      int kb = (t + 1) * 32;
      gl_lds16(Ag + kb, Ab[cur ^ 1] + wave * 512);
      gl_lds16(Bg + kb, Bb[cur ^ 1] + wave * 512);
      gl_lds16(Bg + kb + 64 * DMODEL, Bb[cur ^ 1] + 2048 + wave * 512);
    }
    short8 a[2], b[4];
#pragma unroll
    for (int i = 0; i < 2; ++i)
      a[i] = *(const short8*)(Ab[cur] + (wr * 32 + i * 16 + lr) * 32 + quad * 8);
#pragma unroll
    for (int j = 0; j < 4; ++j)
      b[j] = *(const short8*)(Bb[cur] + (wc * 64 + j * 16 + lr) * 32 + quad * 8);
    if (isV) {
      // swapped operands: acc holds C^T fragment for coalesced vT store
#pragma unroll
      for (int i = 0; i < 2; ++i)
#pragma unroll
        for (int j = 0; j < 4; ++j)
          acc[i][j] = __builtin_amdgcn_mfma_f32_16x16x32_bf16(b[j], a[i], acc[i][j], 0, 0, 0);
    } else {
#pragma unroll
      for (int i = 0; i < 2; ++i)
#pragma unroll
        for (int j = 0; j < 4; ++j)
          acc[i][j] = __builtin_amdgcn_mfma_f32_16x16x32_bf16(a[i], b[j], acc[i][j], 0, 0, 0);
    }
    __syncthreads();  // drains next-tile staging AND protects cur before overwrite
    cur ^= 1;
  }

  if (!isV) {
    short* out = (n0 < DMODEL) ? q : k;
    int nbase = n0 & (DMODEL - 1);
#pragma unroll
    for (int i = 0; i < 2; ++i)
#pragma unroll
      for (int j = 0; j < 4; ++j) {
        int n = nbase + wc * 64 + j * 16 + lr;
        int hh = n >> 6, d = n & 63;
        size_t base = ((size_t)hh * SEQ + m0 + wr * 32 + i * 16 + quad * 4) * HDIM + d;
#pragma unroll
        for (int r = 0; r < 4; ++r) out[base + (size_t)r * HDIM] = f2bf(acc[i][j][r]);
      }
  } else {
    int nbase = n0 - 2 * DMODEL;
#pragma unroll
    for (int i = 0; i < 2; ++i) {
      int sidx = m0 + wr * 32 + i * 16 + lr;
#pragma unroll
      for (int j = 0; j < 4; ++j) {
        int n = nbase + wc * 64 + j * 16 + quad * 4;
#pragma unroll
        for (int r = 0; r < 4; ++r) vT[(size_t)(n + r) * SEQ + sidx] = f2bf(acc[i][j][r]);
      }
    }
  }
}

// ---------------- Fused attention: TWO-PASS streaming softmax ----------------
// Block = 1 head x 16 Q rows, 4 waves each own 512 cols (4 chunks of 128).
// Pass 1: chunked QK^T, online (m,l) per lane, scores DISCARDED (frees 128 VGPRs).
// Pass 2: recompute chunk scores -> probs (LDS transpose, coalesced nt store) -> PV.
// VGPR capped at 128 (4 waves/SIMD); LDS 34.3 KB (ctx-reduce overlaid on pf).
#define PSTRF 132  // fp32 row stride, padded

__global__ __launch_bounds__(256, 4) void attn_fused_kernel(const short* __restrict__ q,
                                                            const short* __restrict__ k,
                                                            const short* __restrict__ vT,
                                                            float* __restrict__ probs,
                                                            float* __restrict__ ctx) {
  __shared__ float pf[4][16 * PSTRF];  // wave-private fp32 chunk / ctx-partial (overlaid)
  __shared__ float wm[4][16], wl[4][16];

  int h = blockIdx.y;
  int m0 = blockIdx.x * 16;
  int wave = threadIdx.x >> 6, lane = threadIdx.x & 63;
  int lr = lane & 15, quad = lane >> 4;
  int nb = wave * 512;

  const short* Q = q + ((size_t)h * SEQ + m0 + lr) * HDIM + quad * 8;
  short8 qa0 = *(const short8*)(Q);
  short8 qa1 = *(const short8*)(Q + 32);
  const short* K = k + (size_t)h * SEQ * HDIM + quad * 8;

  // ---- pass 1: online max/sum, per-lane over its 32 cols ----
  float mrow[4], lrow[4];
#pragma unroll
  for (int r = 0; r < 4; ++r) { mrow[r] = -3.4e38f; lrow[r] = 0.f; }

#pragma unroll 1
  for (int c = 0; c < 4; ++c) {
    floatx4 s[8];
#pragma unroll
    for (int f = 0; f < 8; ++f) {
      const short* Kr = K + (size_t)(nb + c * 128 + f * 16 + lr) * HDIM;
      short8 b0 = *(const short8*)(Kr);
      short8 b1 = *(const short8*)(Kr + 32);
      floatx4 t = {};
      t = __builtin_amdgcn_mfma_f32_16x16x32_bf16(qa0, b0, t, 0, 0, 0);
      s[f] = __builtin_amdgcn_mfma_f32_16x16x32_bf16(qa1, b1, t, 0, 0, 0);
    }
#pragma unroll
    for (int r = 0; r < 4; ++r) {
      float cm = s[0][r];
#pragma unroll
      for (int f = 1; f < 8; ++f) cm = fmaxf(cm, s[f][r]);
      cm *= 0.125f;
      float mn = fmaxf(mrow[r], cm);
      float sum = 0.f;
#pragma unroll
      for (int f = 0; f < 8; ++f) sum += __expf(s[f][r] * 0.125f - mn);
      lrow[r] = lrow[r] * __expf(mrow[r] - mn) + sum;
      mrow[r] = mn;
    }
  }

  // cross-lane combine (within 16-lane row group)
#pragma unroll
  for (int off = 8; off >= 1; off >>= 1)
#pragma unroll
    for (int r = 0; r < 4; ++r) {
      float om = __shfl_xor(mrow[r], off);
      float ol = __shfl_xor(lrow[r], off);
      float mn = fmaxf(mrow[r], om);
      lrow[r] = lrow[r] * __expf(mrow[r] - mn) + ol * __expf(om - mn);
      mrow[r] = mn;
    }
  if (lr == 0)
#pragma unroll
    for (int r = 0; r < 4; ++r) {
      wm[wave][quad * 4 + r] = mrow[r];
      wl[wave][quad * 4 + r] = lrow[r];
    }
  __syncthreads();
  float inv[4];
#pragma unroll
  for (int r = 0; r < 4; ++r) {
    int row = quad * 4 + r;
    float m4 = fmaxf(fmaxf(wm[0][row], wm[1][row]), fmaxf(wm[2][row], wm[3][row]));
    float l4 = wl[0][row] * __expf(wm[0][row] - m4) + wl[1][row] * __expf(wm[1][row] - m4) +
               wl[2][row] * __expf(wm[2][row] - m4) + wl[3][row] * __expf(wm[3][row] - m4);
    mrow[r] = m4;
    inv[r] = 1.0f / l4;
  }

  // ---- pass 2: recompute scores per chunk -> probs + PV ----
  float* pw = pf[wave];
  const short* Vb = vT + (size_t)h * HDIM * SEQ;
  floatx4 cacc[4] = {};
  int prow = lane >> 5;    // 0/1
  int pchunk = lane & 31;  // float4 index within 128-col row

#pragma unroll 1
  for (int c = 0; c < 4; ++c) {
    floatx4 s[8];
#pragma unroll
    for (int f = 0; f < 8; ++f) {
      const short* Kr = K + (size_t)(nb + c * 128 + f * 16 + lr) * HDIM;
      short8 b0 = *(const short8*)(Kr);
      short8 b1 = *(const short8*)(Kr + 32);
      floatx4 t = {};
      t = __builtin_amdgcn_mfma_f32_16x16x32_bf16(qa0, b0, t, 0, 0, 0);
      s[f] = __builtin_amdgcn_mfma_f32_16x16x32_bf16(qa1, b1, t, 0, 0, 0);
    }
    // probs -> wave-private LDS (fp32), transposed layout
#pragma unroll
    for (int f = 0; f < 8; ++f)
#pragma unroll
      for (int r = 0; r < 4; ++r)
        pw[(quad * 4 + r) * PSTRF + f * 16 + lr] = __expf(s[f][r] * 0.125f - mrow[r]) * inv[r];
    // coalesced non-temporal probs store (512B contiguous per row segment)
#pragma unroll
    for (int i = 0; i < 8; ++i) {
      int row = i * 2 + prow;
      floatx4 v4 = *(const floatx4*)(pw + row * PSTRF + pchunk * 4);
      __builtin_nontemporal_store(
          v4, (floatx4*)(probs + ((size_t)h * SEQ + m0 + row) * SEQ + nb + c * 128 + pchunk * 4));
    }
    // PV: read fp32 P, convert to bf16 A-frag, MFMA against vT
#pragma unroll
    for (int kt = 0; kt < 128; kt += 32) {
      const float* pa = pw + lr * PSTRF + kt + quad * 8;
      floatx4 p0 = *(const floatx4*)(pa);
      floatx4 p1 = *(const floatx4*)(pa + 4);
      short8 a;
#pragma unroll
      for (int j = 0; j < 4; ++j) {
        a[j] = f2bf(p0[j]);
        a[4 + j] = f2bf(p1[j]);
      }
#pragma unroll
      for (int f = 0; f < 4; ++f) {
        short8 b = *(const short8*)(Vb + (size_t)(f * 16 + lr) * SEQ + nb + c * 128 + kt + quad * 8);
        cacc[f] = __builtin_amdgcn_mfma_f32_16x16x32_bf16(a, b, cacc[f], 0, 0, 0);
      }
    }
  }

  // ---- cross-wave ctx reduction (overlaid on pf: same-wave DS is in-order) ----
  float* part = pf[wave];
#pragma unroll
  for (int f = 0; f < 4; ++f)
#pragma unroll
    for (int r = 0; r < 4; ++r) part[(quad * 4 + r) * 64 + f * 16 + lr] = cacc[f][r];
  __syncthreads();
  for (int e = threadIdx.x; e < 16 * 64; e += 256) {
    int m = e >> 6, d = e & 63;
    float v = pf[0][m * 64 + d] + pf[1][m * 64 + d] + pf[2][m * 64 + d] + pf[3][m * 64 + d];
    ctx[(size_t)(m0 + m) * DMODEL + h * HDIM + d] = v;
  }
}

extern "C" void kernel_launch(void* const* d_in, const int* in_sizes, int n_in,
                              void* d_out, int out_size, void* d_ws, size_t ws_size,
                              hipStream_t stream) {
  const float* X = (const float*)d_in[0];
  const float* Wq = (const float*)d_in[1];
  const float* Wk = (const float*)d_in[2];
  const float* Wv = (const float*)d_in[3];

  float* ctx = (float*)d_out;
  float* probs = (float*)d_out + (size_t)SEQ * DMODEL;

  short* Xb = (short*)d_ws;                      // [2048][1024] bf16
  short* Wt = Xb + (size_t)SEQ * DMODEL;         // [3*1024][1024] bf16 (B^T)
  short* qb = Wt + (size_t)3 * DMODEL * DMODEL;  // [16][2048][64]
  short* kb = qb + (size_t)NHEADS * SEQ * HDIM;  // [16][2048][64]
  short* vT = kb + (size_t)NHEADS * SEQ * HDIM;  // [16][64][2048]

  cast_bf16_kernel<<<(SEQ * DMODEL + 255) / 256, 256, 0, stream>>>(X, Xb, SEQ * DMODEL);
  dim3 tb(32, 8), tg(32, 32);
  transpose_cast_kernel<<<tg, tb, 0, stream>>>(Wq, Wt);
  transpose_cast_kernel<<<tg, tb, 0, stream>>>(Wk, Wt + (size_t)DMODEL * DMODEL);
  transpose_cast_kernel<<<tg, tb, 0, stream>>>(Wv, Wt + (size_t)2 * DMODEL * DMODEL);

  qkv_gemm_kernel<<<dim3(3 * DMODEL / 128, SEQ / 64), 256, 0, stream>>>(Xb, Wt, qb, kb, vT);
  attn_fused_kernel<<<dim3(SEQ / 16, NHEADS), 256, 0, stream>>>(qb, kb, vT, probs, ctx);
}